// Round 1
// baseline (19587.552 us; speedup 1.0000x reference)
//
#include <hip/hip_runtime.h>

// RVAE on MI355X. Design notes (KERNEL-tier):
//  - 128 persistent WGs (one per batch row); recurrent weights (768x256 f16)
//    live in 128 VGPRs/thread at 768 thr/WG (12 waves, ~165 reg budget at
//    3 waves/SIMD). Streaming weights from L2 would be >20ms (per-CU L2 BW
//    ~150GB/s vs 786KB/step); register residency removes that wall.
//  - All dot products via v_dot2_f32_f16 (f16 pairs, f32 accumulate).
//    Activations/gates/reductions all f32. Only matvec operands are f16.
//  - Encoder fuses the xh -> Wz[:,H:2H] projection (8 floats/step) so the
//    full xh[L,B,256] (268MB) is never materialized.
//  - Decoder split: decA (phi GRU + z sample + kld) then decB (theta GRU +
//    x linears + recon + y_loc), sequential kernels; z passes via ws as
//    packed f16 pairs. (Whh2+Whh3 = 768KB can't both fit one CU's RF.)
//  - Static LDS kept < 64KB per kernel.

typedef unsigned int uint32;
typedef _Float16 half2v __attribute__((ext_vector_type(2)));

#define LOG2PI_F 1.8378770664093453f

__device__ __forceinline__ float dot2f(uint32 w, uint32 h, float acc) {
#if __has_builtin(__builtin_amdgcn_fdot2)
  return __builtin_amdgcn_fdot2(__builtin_bit_cast(half2v, w),
                                __builtin_bit_cast(half2v, h), acc, false);
#else
  half2v a = __builtin_bit_cast(half2v, w);
  half2v b = __builtin_bit_cast(half2v, h);
  return acc + (float)a.x * (float)b.x + (float)a.y * (float)b.y;
#endif
}

__device__ __forceinline__ uint32 packh2(float a, float b) {
  half2v v;
  v.x = (_Float16)a;
  v.y = (_Float16)b;
  return __builtin_bit_cast(uint32, v);
}

__device__ __forceinline__ float wredsum64(float v) {
  v += __shfl_xor(v, 32); v += __shfl_xor(v, 16); v += __shfl_xor(v, 8);
  v += __shfl_xor(v, 4);  v += __shfl_xor(v, 2);  v += __shfl_xor(v, 1);
  return v;
}

__device__ __forceinline__ float sigm(float x) { return 1.0f / (1.0f + expf(-x)); }
__device__ __forceinline__ float tanh_(float x) { return 1.0f - 2.0f / (expf(2.0f * x) + 1.0f); }

// ---------------- prep: repack weights into ws ----------------
// wp1/wp2/wp3:  [128][768] uint32, pair (Whh[k][2i],Whh[k][2i+1]) as f16x2
// wih1t: [16][768] f16x2 pairs of Wih1[k][2i..]; wih2t/wih3t: [2][768]
// wz1t/wz2t: [256][9] f32 (padded col for bank spread) = Wz{l,s}[o][(0|256)+i]
// wxp: [128][64] f16x2 pairs over i of (Wxl;Wxs)[o][2i..]
__global__ void prep_kernel(const float* __restrict__ Wih1, const float* __restrict__ Whh1,
                            const float* __restrict__ Wih2, const float* __restrict__ Whh2,
                            const float* __restrict__ Wih3, const float* __restrict__ Whh3,
                            const float* __restrict__ Wzl, const float* __restrict__ Wzs,
                            const float* __restrict__ Wxl, const float* __restrict__ Wxs,
                            uint32* wp1, uint32* wp2, uint32* wp3,
                            uint32* wih1t, uint32* wih2t, uint32* wih3t,
                            float* wz1t, float* wz2t, uint32* wxp) {
  int id = blockIdx.x * blockDim.x + threadIdx.x;
  int str = gridDim.x * blockDim.x;
  for (int n = id; n < 128 * 768; n += str) {
    int i = n / 768, k = n % 768;
    wp1[n] = packh2(Whh1[k * 256 + 2 * i], Whh1[k * 256 + 2 * i + 1]);
    wp2[n] = packh2(Whh2[k * 256 + 2 * i], Whh2[k * 256 + 2 * i + 1]);
    wp3[n] = packh2(Whh3[k * 256 + 2 * i], Whh3[k * 256 + 2 * i + 1]);
  }
  for (int n = id; n < 16 * 768; n += str) {
    int i = n / 768, k = n % 768;
    wih1t[n] = packh2(Wih1[k * 32 + 2 * i], Wih1[k * 32 + 2 * i + 1]);
  }
  for (int n = id; n < 2 * 768; n += str) {
    int i = n / 768, k = n % 768;
    wih2t[n] = packh2(Wih2[k * 4 + 2 * i], Wih2[k * 4 + 2 * i + 1]);
    wih3t[n] = packh2(Wih3[k * 4 + 2 * i], Wih3[k * 4 + 2 * i + 1]);
  }
  for (int n = id; n < 256 * 8; n += str) {
    int i = n >> 3, o = n & 7;
    wz1t[i * 9 + o] = (o < 4) ? Wzl[o * 512 + i] : Wzs[(o - 4) * 512 + i];
    wz2t[i * 9 + o] = (o < 4) ? Wzl[o * 512 + 256 + i] : Wzs[(o - 4) * 512 + 256 + i];
  }
  for (int n = id; n < 128 * 64; n += str) {
    int i2 = n >> 6, o = n & 63;
    float a = (o < 32) ? Wxl[o * 256 + 2 * i2] : Wxs[(o - 32) * 256 + 2 * i2];
    float b = (o < 32) ? Wxl[o * 256 + 2 * i2 + 1] : Wxs[(o - 32) * 256 + 2 * i2 + 1];
    wxp[n] = packh2(a, b);
  }
}

// ---------------- encoder: reverse GRU + fused xh->Wz projection ----------------
__global__ __launch_bounds__(768) void enc_kernel(
    const float* __restrict__ x, const float* __restrict__ bih1,
    const float* __restrict__ bhh1, const uint32* __restrict__ wp1,
    const uint32* __restrict__ wih1t, const float* __restrict__ wz2t,
    float* __restrict__ zx) {
  const int b = blockIdx.x, k = threadIdx.x;
  __shared__ uint32 wih[16 * 768];        // 48KB: Wih1^T f16 pairs
  __shared__ float wz[256 * 9];           // 9KB:  Wz[:,H:] proj, f32 padded
  __shared__ float s_rz[512];             // r,z preactivation sums
  __shared__ float gin[256], ghn[256];    // n-gate input/hidden parts
  __shared__ float h[256];                // f32 canonical state
  __shared__ __align__(16) uint32 hpk[128]; // f16x2 copy for dot2
  __shared__ uint32 xpk[16];              // x_t as f16x2

  uint32 wr[128];                         // Whh1 row k, f16 pairs (registers)
#pragma unroll
  for (int i = 0; i < 128; ++i) wr[i] = wp1[i * 768 + k];
  const float bi = bih1[k], bh = bhh1[k];
  for (int i = k; i < 16 * 768; i += 768) wih[i] = wih1t[i];
  for (int i = k; i < 256 * 9; i += 768) wz[i] = wz2t[i];
  if (k < 256) h[k] = 0.0f;
  if (k < 128) hpk[k] = 0u;
  const float* xb = x + (size_t)b * (2048 * 32);
  if (k < 16) xpk[k] = packh2(xb[2047 * 32 + 2 * k], xb[2047 * 32 + 2 * k + 1]);
  __syncthreads();

  for (int t = 2047; t >= 0; --t) {
    // phase 1: every thread computes one preactivation row (x-part + h-part)
    float ai = bi;
#pragma unroll
    for (int i = 0; i < 16; ++i) ai = dot2f(wih[i * 768 + k], xpk[i], ai);
    float a0 = 0.f, a1 = 0.f, a2 = 0.f, a3 = 0.f;
#pragma unroll
    for (int i = 0; i < 128; i += 4) {
      uint4 hv = *(const uint4*)&hpk[i];
      a0 = dot2f(wr[i], hv.x, a0);
      a1 = dot2f(wr[i + 1], hv.y, a1);
      a2 = dot2f(wr[i + 2], hv.z, a2);
      a3 = dot2f(wr[i + 3], hv.w, a3);
    }
    float ah = bh + ((a0 + a1) + (a2 + a3));
    if (k < 512) s_rz[k] = ai + ah;
    else { gin[k - 512] = ai; ghn[k - 512] = ah; }
    __syncthreads();
    // phase 2: gates (threads 0..255), pack f16 copy via lane shuffle
    if (k < 256) {
      float r = sigm(s_rz[k]);
      float z = sigm(s_rz[k + 256]);
      float n = tanh_(gin[k] + r * ghn[k]);
      float hn = (1.0f - z) * n + z * h[k];
      h[k] = hn;
      float other = __shfl_xor(hn, 1);
      if ((k & 1) == 0) hpk[k >> 1] = packh2(hn, other);
    }
    __syncthreads();
    // phase 3: fused projection (waves 4..11) + stage next x (wave 2 lanes)
    if (k >= 256) {
      int o = (k - 256) >> 6, l = k & 63;
      float s = 0.f;
#pragma unroll
      for (int m = 0; m < 4; ++m) { int i = l + 64 * m; s += h[i] * wz[i * 9 + o]; }
      s = wredsum64(s);
      if (l == 0) zx[((size_t)t * 128 + b) * 8 + o] = s;
    } else if (k >= 144 && k < 160) {
      if (t > 0) {
        int i = k - 144;
        xpk[i] = packh2(xb[(t - 1) * 32 + 2 * i], xb[(t - 1) * 32 + 2 * i + 1]);
      }
    }
    __syncthreads();
  }
}

// ---------------- decoder stage A: phi GRU + z sample + kld ----------------
__global__ __launch_bounds__(768) void decA_kernel(
    const float* __restrict__ eps, const float* __restrict__ bih2,
    const float* __restrict__ bhh2, const uint32* __restrict__ wp2,
    const uint32* __restrict__ wih2t, const float* __restrict__ wz1t,
    const float* __restrict__ bzl, const float* __restrict__ bzs,
    const float* __restrict__ zx, uint32* __restrict__ zbuf,
    float* __restrict__ kld_out) {
  const int b = blockIdx.x, k = threadIdx.x;
  __shared__ uint32 wih[2 * 768];
  __shared__ float wz[256 * 9];
  __shared__ float s_rz[512];
  __shared__ float gin[256], ghn[256];
  __shared__ float h[256];
  __shared__ __align__(16) uint32 hpk[128];
  __shared__ float zl[8];
  __shared__ uint32 zpk[2];

  uint32 wr[128];
#pragma unroll
  for (int i = 0; i < 128; ++i) wr[i] = wp2[i * 768 + k];
  const float bi = bih2[k], bh = bhh2[k];
  for (int i = k; i < 2 * 768; i += 768) wih[i] = wih2t[i];
  for (int i = k; i < 256 * 9; i += 768) wz[i] = wz1t[i];
  if (k < 256) h[k] = 0.0f;
  if (k < 128) hpk[k] = 0u;
  if (k < 2) zpk[k] = 0u;
  float kacc = 0.0f;
  __syncthreads();

  for (int t = 0; t < 2048; ++t) {
    float ai = bi;
    ai = dot2f(wih[k], zpk[0], ai);
    ai = dot2f(wih[768 + k], zpk[1], ai);
    float a0 = 0.f, a1 = 0.f, a2 = 0.f, a3 = 0.f;
#pragma unroll
    for (int i = 0; i < 128; i += 4) {
      uint4 hv = *(const uint4*)&hpk[i];
      a0 = dot2f(wr[i], hv.x, a0);
      a1 = dot2f(wr[i + 1], hv.y, a1);
      a2 = dot2f(wr[i + 2], hv.z, a2);
      a3 = dot2f(wr[i + 3], hv.w, a3);
    }
    float ah = bh + ((a0 + a1) + (a2 + a3));
    if (k < 512) s_rz[k] = ai + ah;
    else { gin[k - 512] = ai; ghn[k - 512] = ah; }
    __syncthreads();
    if (k < 256) {
      float r = sigm(s_rz[k]);
      float z = sigm(s_rz[k + 256]);
      float n = tanh_(gin[k] + r * ghn[k]);
      float hn = (1.0f - z) * n + z * h[k];
      h[k] = hn;
      float other = __shfl_xor(hn, 1);
      if ((k & 1) == 0) hpk[k >> 1] = packh2(hn, other);
    }
    __syncthreads();
    if (k >= 256) {  // z linear over new phi_h (f32 path)
      int o = (k - 256) >> 6, l = k & 63;
      float s = 0.f;
#pragma unroll
      for (int m = 0; m < 4; ++m) { int i = l + 64 * m; s += h[i] * wz[i * 9 + o]; }
      s = wredsum64(s);
      if (l == 0) zl[o] = s;
    }
    __syncthreads();
    if (k < 4) {
      const size_t tb = (size_t)t * 128 + b;
      float loc = zl[k] + bzl[k] + zx[tb * 8 + k];
      float lv  = zl[k + 4] + bzs[k] + zx[tb * 8 + k + 4];
      float sc = expf(0.5f * lv);
      float zv = loc + sc * eps[tb * 4 + k];
      kacc += 0.5f * (sc * sc + loc * loc - 1.0f - lv);
      float other = __shfl_xor(zv, 1);
      if ((k & 1) == 0) {
        uint32 pk = packh2(zv, other);
        zpk[k >> 1] = pk;
        zbuf[tb * 2 + (k >> 1)] = pk;
      }
    }
    __syncthreads();
  }
  if (k < 4) atomicAdd(kld_out, kacc);
}

// ---------------- decoder stage B: theta GRU + x linears + recon ----------------
__global__ __launch_bounds__(768) void decB_kernel(
    const float* __restrict__ x, const float* __restrict__ bih3,
    const float* __restrict__ bhh3, const uint32* __restrict__ wp3,
    const uint32* __restrict__ wih3t, const uint32* __restrict__ wxp_g,
    const float* __restrict__ bxl, const float* __restrict__ bxs,
    const uint32* __restrict__ zbuf, float* __restrict__ y,
    float* __restrict__ recon_out) {
  const int b = blockIdx.x, k = threadIdx.x;
  __shared__ uint32 wxp[128 * 64];        // 32KB (Wxl;Wxs)^T f16 pairs
  __shared__ uint32 wih[2 * 768];
  __shared__ float s_rz[512];
  __shared__ float gin[256], ghn[256];
  __shared__ float h[256];
  __shared__ __align__(16) uint32 hpk[128];
  __shared__ float p[8 * 64];
  __shared__ float xl[64];
  __shared__ uint32 zpk[2];

  uint32 wr[128];
#pragma unroll
  for (int i = 0; i < 128; ++i) wr[i] = wp3[i * 768 + k];
  const float bi = bih3[k], bh = bhh3[k];
  for (int i = k; i < 128 * 64; i += 768) wxp[i] = wxp_g[i];
  for (int i = k; i < 2 * 768; i += 768) wih[i] = wih3t[i];
  if (k < 256) h[k] = 0.0f;
  if (k < 128) hpk[k] = 0u;
  if (k < 2) zpk[k] = zbuf[(size_t)b * 2 + k];  // t = 0
  float racc = 0.0f;
  const float* xb = x + (size_t)b * (2048 * 32);
  float* yb = y + (size_t)b * (2048 * 32);
  __syncthreads();

  for (int t = 0; t < 2048; ++t) {
    float ai = bi;
    ai = dot2f(wih[k], zpk[0], ai);
    ai = dot2f(wih[768 + k], zpk[1], ai);
    float a0 = 0.f, a1 = 0.f, a2 = 0.f, a3 = 0.f;
#pragma unroll
    for (int i = 0; i < 128; i += 4) {
      uint4 hv = *(const uint4*)&hpk[i];
      a0 = dot2f(wr[i], hv.x, a0);
      a1 = dot2f(wr[i + 1], hv.y, a1);
      a2 = dot2f(wr[i + 2], hv.z, a2);
      a3 = dot2f(wr[i + 3], hv.w, a3);
    }
    float ah = bh + ((a0 + a1) + (a2 + a3));
    if (k < 512) s_rz[k] = ai + ah;
    else { gin[k - 512] = ai; ghn[k - 512] = ah; }
    __syncthreads();
    if (k < 256) {
      float r = sigm(s_rz[k]);
      float z = sigm(s_rz[k + 256]);
      float n = tanh_(gin[k] + r * ghn[k]);
      float hn = (1.0f - z) * n + z * h[k];
      h[k] = hn;
      float other = __shfl_xor(hn, 1);
      if ((k & 1) == 0) hpk[k >> 1] = packh2(hn, other);
    }
    __syncthreads();
    if (k >= 256) {  // x-linear partials over new theta_h (f16 dot2 w/ hpk)
      int m = (k - 256) >> 6, o = k & 63;
      float s0 = 0.f, s1 = 0.f;
#pragma unroll
      for (int i2 = m; i2 < 128; i2 += 16) {
        s0 = dot2f(wxp[i2 * 64 + o], hpk[i2], s0);
        s1 = dot2f(wxp[(i2 + 8) * 64 + o], hpk[i2 + 8], s1);
      }
      p[m * 64 + o] = s0 + s1;
    }
    __syncthreads();
    if (k < 64) {
      float s = 0.f;
#pragma unroll
      for (int m = 0; m < 8; ++m) s += p[m * 64 + k];
      xl[k] = s + ((k < 32) ? bxl[k] : bxs[k - 32]);
    }
    __syncthreads();
    if (k < 32) {
      float loc = xl[k], lv = xl[k + 32];
      yb[t * 32 + k] = loc;
      float d = xb[t * 32 + k] - loc;
      racc += 0.5f * d * d * expf(-lv) + 0.5f * lv + 0.5f * LOG2PI_F;
    } else if (k >= 64 && k < 66) {
      if (t + 1 < 2048) zpk[k - 64] = zbuf[((size_t)(t + 1) * 128 + b) * 2 + (k - 64)];
    }
    __syncthreads();
  }
  if (k < 32) {
    racc += __shfl_xor(racc, 16); racc += __shfl_xor(racc, 8);
    racc += __shfl_xor(racc, 4);  racc += __shfl_xor(racc, 2);
    racc += __shfl_xor(racc, 1);
    if (k == 0) atomicAdd(recon_out, racc);
  }
}

// ---------------- launcher ----------------
extern "C" void kernel_launch(void* const* d_in, const int* in_sizes, int n_in,
                              void* d_out, int out_size, void* d_ws, size_t ws_size,
                              hipStream_t stream) {
  const float* x    = (const float*)d_in[0];
  const float* eps  = (const float*)d_in[1];
  const float* Wih1 = (const float*)d_in[2];
  const float* Whh1 = (const float*)d_in[3];
  const float* bih1 = (const float*)d_in[4];
  const float* bhh1 = (const float*)d_in[5];
  const float* Wih2 = (const float*)d_in[6];
  const float* Whh2 = (const float*)d_in[7];
  const float* bih2 = (const float*)d_in[8];
  const float* bhh2 = (const float*)d_in[9];
  const float* Wih3 = (const float*)d_in[10];
  const float* Whh3 = (const float*)d_in[11];
  const float* bih3 = (const float*)d_in[12];
  const float* bhh3 = (const float*)d_in[13];
  const float* Wzl  = (const float*)d_in[14];
  const float* bzl  = (const float*)d_in[15];
  const float* Wzs  = (const float*)d_in[16];
  const float* bzs  = (const float*)d_in[17];
  const float* Wxl  = (const float*)d_in[18];
  const float* bxl  = (const float*)d_in[19];
  const float* Wxs  = (const float*)d_in[20];
  const float* bxs  = (const float*)d_in[21];

  float* ws = (float*)d_ws;
  uint32* wp1   = (uint32*)(ws + 0);        // 98304
  uint32* wp2   = (uint32*)(ws + 98304);    // 98304
  uint32* wp3   = (uint32*)(ws + 196608);   // 98304
  uint32* wih1t = (uint32*)(ws + 294912);   // 12288
  uint32* wih2t = (uint32*)(ws + 307200);   // 1536
  uint32* wih3t = (uint32*)(ws + 308736);   // 1536
  float*  wz1t  = ws + 310272;              // 2304
  float*  wz2t  = ws + 312576;              // 2304
  uint32* wxp   = (uint32*)(ws + 314880);   // 8192
  float*  zx    = ws + 323072;              // 2097152  [L][B][8]
  uint32* zbuf  = (uint32*)(ws + 2420224);  // 524288   [L][B] f16x2 pairs
  // total ~11.8 MB of ws

  float* out = (float*)d_out;  // [B*L*F] y_loc, then recon, kld
  hipMemsetAsync(out + 8388608, 0, 8, stream);  // zero recon/kld accumulators

  prep_kernel<<<128, 256, 0, stream>>>(Wih1, Whh1, Wih2, Whh2, Wih3, Whh3,
                                       Wzl, Wzs, Wxl, Wxs,
                                       wp1, wp2, wp3, wih1t, wih2t, wih3t,
                                       wz1t, wz2t, wxp);
  enc_kernel<<<128, 768, 0, stream>>>(x, bih1, bhh1, wp1, wih1t, wz2t, zx);
  decA_kernel<<<128, 768, 0, stream>>>(eps, bih2, bhh2, wp2, wih2t, wz1t,
                                       bzl, bzs, zx, zbuf, out + 8388609);
  decB_kernel<<<128, 768, 0, stream>>>(x, bih3, bhh3, wp3, wih3t, wxp,
                                       bxl, bxs, zbuf, out, out + 8388608);
}